// Round 1
// baseline (723.227 us; speedup 1.0000x reference)
//
#include <hip/hip_runtime.h>
#include <hip/hip_bf16.h>
#include <math.h>

// ---------------------------------------------------------------------------
// SlotAttention (B=32,N=4096,C=768,D=64,H=128,S=7, 3 iters)
// Stage 1: k,v = LN(x) @ [Wk|Wv]  as bf16 MFMA GEMM on RAW x:
//   xn = (x-m)*rstd*g + b  =>  k = rstd*(x @ (g*W)) - m*rstd*sum(g*W) + sum(b*W)
//   (per-row scalars m,rstd computed during staging; rank-1 epilogue)
// Stage 2 (x3): logits/softmax-over-S/weights + num/den atomics; GRU+MLP+next-q
// ---------------------------------------------------------------------------

typedef __bf16 bf16x8 __attribute__((ext_vector_type(8)));
typedef float  f32x4  __attribute__((ext_vector_type(4)));

#define NB 32
#define NN 4096
#define NC 768
#define ND 64
#define NS 7

__device__ __forceinline__ float wave_sum64(float v) {
#pragma unroll
  for (int o = 32; o > 0; o >>= 1) v += __shfl_xor(v, o, 64);
  return v;
}

// LN(h; g_sl,b_sl) @ Wq for one (b,s) row; 64-thread block, h = this thread's elem
__device__ __forceinline__ void slots_ln_q(float h, int t, const float* g_sl,
                                           const float* b_sl, const float* Wq,
                                           float* y_s, float* q_out) {
  float m = wave_sum64(h) * (1.0f / 64.0f);
  float dx = h - m;
  float var = wave_sum64(dx * dx) * (1.0f / 64.0f);
  float rstd = rsqrtf(var + 1e-5f);
  y_s[t] = dx * rstd * g_sl[t] + b_sl[t];
  __syncthreads();
  float q = 0.f;
#pragma unroll 8
  for (int i = 0; i < 64; ++i) q = fmaf(y_s[i], Wq[i * 64 + t], q);
  q_out[t] = q;
}

// ---------------------------------------------------------------------------
// prep: blocks 0..127  -> GWt[d][c] = bf16(g_in[c]*W[c,d]) (transposed, bf16),
//                         GWsum[d] = sum_c g*W, BW[d] = sum_c b*W
//       blocks 128..351 -> per (b,s): copy slots -> ws, zero num/den, initial q
// ---------------------------------------------------------------------------
__global__ __launch_bounds__(64) void k_prep(
    const float* __restrict__ Wk, const float* __restrict__ Wv,
    const float* __restrict__ g_in, const float* __restrict__ b_in,
    const float* __restrict__ slots_in, const float* __restrict__ g_sl,
    const float* __restrict__ b_sl, const float* __restrict__ Wq,
    __bf16* __restrict__ GWt, float* __restrict__ GWsum, float* __restrict__ BW,
    float* __restrict__ slots_ws, float* __restrict__ q_ws,
    float* __restrict__ num, float* __restrict__ den) {
  __shared__ float y_s[64];
  int t = threadIdx.x;
  int bid = blockIdx.x;
  if (bid < 128) {
    int d = bid;
    const float* W = (d < 64) ? (Wk + d) : (Wv + (d - 64));
    float sgw = 0.f, sbw = 0.f;
    for (int j = 0; j < 12; ++j) {
      int c = t + 64 * j;
      float w = W[(size_t)c * 64];
      float gw = g_in[c] * w;
      GWt[(size_t)d * NC + c] = (__bf16)gw;
      sgw += gw;
      sbw += b_in[c] * w;
    }
    sgw = wave_sum64(sgw);
    sbw = wave_sum64(sbw);
    if (t == 0) { GWsum[d] = sgw; BW[d] = sbw; }
  } else {
    int bs = bid - 128;
    float h = slots_in[bs * 64 + t];
    slots_ws[bs * 64 + t] = h;
    num[bs * 64 + t] = 0.f;
    if (t == 0) den[bs] = 0.f;
    slots_ln_q(h, t, g_sl, b_sl, Wq, y_s, q_ws + bs * 64);
  }
}

// ---------------------------------------------------------------------------
// GEMM: (131072 x 768) @ (768 x 128) bf16 MFMA, fused LN epilogue -> kbuf,vbuf
// 128x128 block tile, BK=64, 4 waves (2x2), each wave 64x64 via 4x4 16x16 tiles
// ---------------------------------------------------------------------------
#define BM 128
#define LDA 72  // bf16 elems; 144 B row stride (16B-aligned)

__global__ __launch_bounds__(256) void k_gemm_kv(
    const float* __restrict__ x, const __bf16* __restrict__ GWt,
    const float* __restrict__ GWsum, const float* __restrict__ BW,
    float* __restrict__ kbuf, float* __restrict__ vbuf) {
  __shared__ __bf16 As[BM * LDA] __attribute__((aligned(16)));
  __shared__ __bf16 Bs[128 * LDA] __attribute__((aligned(16)));
  __shared__ float mean_s[128], rstd_s[128], gws_s[128], bw_s[128];

  int t = threadIdx.x;
  int blk = blockIdx.x;
  int lane = t & 63, wave = t >> 6;
  int wr = wave >> 1, wc = wave & 1;
  int grp = lane >> 4, lr = lane & 15;
  int r = t >> 1, half = t & 1;  // staging: row (or B-col) r, 32-elem half

  if (t < 128) { gws_s[t] = GWsum[t]; bw_s[t] = BW[t]; }

  f32x4 acc[4][4] = {};
  float s1 = 0.f, s2 = 0.f;

  const float* xrow = x + (size_t)(blk * BM + r) * NC + half * 32;
  const __bf16* grow = GWt + (size_t)r * NC + half * 32;

  for (int ck = 0; ck < 12; ++ck) {
    __syncthreads();
    {  // stage A: 32 fp32 -> bf16 (+ row sum/sumsq for LN)
      const float4* p4 = (const float4*)(xrow + ck * 64);
      __bf16* dst = &As[r * LDA + half * 32];
#pragma unroll
      for (int j = 0; j < 4; ++j) {
        float4 a = p4[2 * j], b = p4[2 * j + 1];
        bf16x8 pk;
        pk[0] = (__bf16)a.x; pk[1] = (__bf16)a.y; pk[2] = (__bf16)a.z; pk[3] = (__bf16)a.w;
        pk[4] = (__bf16)b.x; pk[5] = (__bf16)b.y; pk[6] = (__bf16)b.z; pk[7] = (__bf16)b.w;
        s1 += (a.x + a.y + a.z + a.w) + (b.x + b.y + b.z + b.w);
        s2 += a.x * a.x + a.y * a.y + a.z * a.z + a.w * a.w +
              b.x * b.x + b.y * b.y + b.z * b.z + b.w * b.w;
        *(bf16x8*)(dst + j * 8) = pk;
      }
    }
    {  // stage B (already bf16, already transposed [col][k]) : raw 16B copies
      const uint4* p4 = (const uint4*)(grow + ck * 64);
      uint4* dst = (uint4*)&Bs[r * LDA + half * 32];
#pragma unroll
      for (int j = 0; j < 4; ++j) dst[j] = p4[j];
    }
    __syncthreads();
#pragma unroll
    for (int kk = 0; kk < 2; ++kk) {
      bf16x8 af[4], bfr[4];
#pragma unroll
      for (int i = 0; i < 4; ++i)
        af[i] = *(const bf16x8*)&As[(wr * 64 + i * 16 + lr) * LDA + kk * 32 + grp * 8];
#pragma unroll
      for (int i = 0; i < 4; ++i)
        bfr[i] = *(const bf16x8*)&Bs[(wc * 64 + i * 16 + lr) * LDA + kk * 32 + grp * 8];
#pragma unroll
      for (int i = 0; i < 4; ++i)
#pragma unroll
        for (int j = 0; j < 4; ++j)
          acc[i][j] = __builtin_amdgcn_mfma_f32_16x16x32_bf16(af[i], bfr[j], acc[i][j], 0, 0, 0);
    }
  }

  // per-row LN stats (thread pair 2r,2r+1 covered row r's halves across chunks)
  s1 += __shfl_xor(s1, 1, 64);
  s2 += __shfl_xor(s2, 1, 64);
  if (half == 0) {
    float m = s1 * (1.0f / 768.0f);
    float var = s2 * (1.0f / 768.0f) - m * m;
    mean_s[r] = m;
    rstd_s[r] = rsqrtf(var + 1e-5f);
  }
  __syncthreads();

  // epilogue: C/D layout col=lane&15, row=(lane>>4)*4+e  [m89/m91 verified]
#pragma unroll
  for (int i = 0; i < 4; ++i) {
#pragma unroll
    for (int j = 0; j < 4; ++j) {
      int colb = wc * 64 + j * 16 + lr;
      float gw = gws_s[colb], bw = bw_s[colb];
      float* obuf = (colb < 64) ? kbuf : vbuf;
      int ocol = colb & 63;
#pragma unroll
      for (int e = 0; e < 4; ++e) {
        int row = wr * 64 + i * 16 + grp * 4 + e;
        float rs = rstd_s[row], m = mean_s[row];
        float val = rs * acc[i][j][e] - m * rs * gw + bw;
        obuf[(size_t)(blk * BM + row) * 64 + ocol] = val;
      }
    }
  }
}

// ---------------------------------------------------------------------------
// attention: per (b, 128-n chunk): logits (q.k), softmax over S=7, weights out,
// den partials, num partials (w @ v) -> atomics
// ---------------------------------------------------------------------------
__global__ __launch_bounds__(256) void k_attn(
    const float* __restrict__ kbuf, const float* __restrict__ vbuf,
    const float* __restrict__ q_ws, float* __restrict__ out_w,
    float* __restrict__ num, float* __restrict__ den) {
  __shared__ float q_s[7 * 64];
  __shared__ float w_s[7 * 130];
  __shared__ float v_s[128 * 68] __attribute__((aligned(16)));
  __shared__ float den_p[28];
  __shared__ float red[7 * 4 * 64];

  int t = threadIdx.x;
  int b = blockIdx.x >> 5;
  int n0 = (blockIdx.x & 31) * 128;

  for (int idx = t; idx < 448; idx += 256) q_s[idx] = q_ws[b * 448 + idx];
  __syncthreads();

  int nl = t >> 1, dh = t & 1;  // lane pair splits the 64-d dot
  float4 kr[8];
  const float4* kp = (const float4*)(kbuf + ((size_t)b * NN + n0 + nl) * 64 + dh * 32);
#pragma unroll
  for (int j = 0; j < 8; ++j) kr[j] = kp[j];

  float lg[7];
#pragma unroll
  for (int s = 0; s < 7; ++s) {
    const float* qv = &q_s[s * 64 + dh * 32];
    float d0 = 0.f;
#pragma unroll
    for (int j = 0; j < 8; ++j) {
      d0 = fmaf(kr[j].x, qv[4 * j + 0], d0);
      d0 = fmaf(kr[j].y, qv[4 * j + 1], d0);
      d0 = fmaf(kr[j].z, qv[4 * j + 2], d0);
      d0 = fmaf(kr[j].w, qv[4 * j + 3], d0);
    }
    d0 += __shfl_xor(d0, 1, 64);
    lg[s] = d0 * 0.125f;  // D^-0.5
  }
  float mx = lg[0];
#pragma unroll
  for (int s = 1; s < 7; ++s) mx = fmaxf(mx, lg[s]);
  float sum = 0.f;
#pragma unroll
  for (int s = 0; s < 7; ++s) { lg[s] = __expf(lg[s] - mx); sum += lg[s]; }
  float inv = 1.0f / sum;
  if (dh == 0) {
#pragma unroll
    for (int s = 0; s < 7; ++s) w_s[s * 130 + nl] = lg[s] * inv;
  }
  __syncthreads();

  // weights -> d_out (every iter; last iteration's values stand)
  for (int idx = t; idx < 896; idx += 256) {
    int s = idx >> 7, n = idx & 127;
    out_w[(size_t)b * 7 * NN + (size_t)s * NN + n0 + n] = w_s[s * 130 + n];
  }
  if (t < 28) {
    int s = t >> 2, qq = t & 3;
    float ds = 0.f;
    for (int j = 0; j < 32; ++j) ds += w_s[s * 130 + qq * 32 + j];
    den_p[t] = ds;
  }
  {  // stage v tile
    const float4* vp = (const float4*)(vbuf + ((size_t)b * NN + n0 + nl) * 64 + dh * 32);
    float4* dst = (float4*)&v_s[nl * 68 + dh * 32];
#pragma unroll
    for (int j = 0; j < 8; ++j) dst[j] = vp[j];
  }
  __syncthreads();
  if (t < 7)
    atomicAdd(&den[b * 7 + t],
              den_p[4 * t] + den_p[4 * t + 1] + den_p[4 * t + 2] + den_p[4 * t + 3]);

  // num[s][d] partials: wave qtr handles 32 n's; w_s read is wave-uniform
  int d = t & 63, qtr = t >> 6;
  float np_[7] = {0, 0, 0, 0, 0, 0, 0};
  for (int j = 0; j < 32; ++j) {
    int n = qtr * 32 + j;
    float vv = v_s[n * 68 + d];
#pragma unroll
    for (int s = 0; s < 7; ++s) np_[s] = fmaf(w_s[s * 130 + n], vv, np_[s]);
  }
#pragma unroll
  for (int s = 0; s < 7; ++s) red[(s * 4 + qtr) * 64 + d] = np_[s];
  __syncthreads();
  for (int idx = t; idx < 448; idx += 256) {
    int s = idx >> 6, dd = idx & 63;
    float sm = red[(s * 4 + 0) * 64 + dd] + red[(s * 4 + 1) * 64 + dd] +
               red[(s * 4 + 2) * 64 + dd] + red[(s * 4 + 3) * 64 + dd];
    atomicAdd(&num[(b * 7 + s) * 64 + dd], sm);
  }
}

// ---------------------------------------------------------------------------
// GRU + residual MLP + next-iteration q; zeroes num/den for next iter.
// one wave per (b,s)
// ---------------------------------------------------------------------------
__global__ __launch_bounds__(64) void k_gru(
    float* __restrict__ num, float* __restrict__ den,
    float* __restrict__ slots_ws, const float* __restrict__ W_ih,
    const float* __restrict__ W_hh, const float* __restrict__ b_ih,
    const float* __restrict__ b_hh, const float* __restrict__ w1,
    const float* __restrict__ bb1, const float* __restrict__ w2,
    const float* __restrict__ bb2, const float* __restrict__ g_mlp,
    const float* __restrict__ b_mlp, const float* __restrict__ g_sl,
    const float* __restrict__ b_sl, const float* __restrict__ Wq,
    float* __restrict__ q_ws, float* __restrict__ out_slots) {
  __shared__ float att_s[64], h_s[64], y_s[64], a_s[128];
  int t = threadIdx.x;
  int bs = blockIdx.x;

  float h = slots_ws[bs * 64 + t];
  float dn = den[bs];
  float at = num[bs * 64 + t] / (dn + 1e-8f);
  att_s[t] = at;
  h_s[t] = h;
  __syncthreads();
  num[bs * 64 + t] = 0.f;  // zero for next iteration
  if (t == 0) den[bs] = 0.f;

  float gi0 = b_ih[t], gi1 = b_ih[64 + t], gi2 = b_ih[128 + t];
  float gh0 = b_hh[t], gh1 = b_hh[64 + t], gh2 = b_hh[128 + t];
#pragma unroll 4
  for (int i = 0; i < 64; ++i) {
    float ai = att_s[i], hi = h_s[i];
    const float* wi = W_ih + i * 192 + t;
    const float* wh = W_hh + i * 192 + t;
    gi0 = fmaf(ai, wi[0], gi0);
    gi1 = fmaf(ai, wi[64], gi1);
    gi2 = fmaf(ai, wi[128], gi2);
    gh0 = fmaf(hi, wh[0], gh0);
    gh1 = fmaf(hi, wh[64], gh1);
    gh2 = fmaf(hi, wh[128], gh2);
  }
  float rr = 1.f / (1.f + __expf(-(gi0 + gh0)));
  float zz = 1.f / (1.f + __expf(-(gi1 + gh1)));
  float nn = tanhf(gi2 + rr * gh2);
  float hn = (1.f - zz) * nn + zz * h;

  // residual MLP with LN
  float m = wave_sum64(hn) * (1.f / 64.f);
  float dx = hn - m;
  float var = wave_sum64(dx * dx) * (1.f / 64.f);
  float rstd = rsqrtf(var + 1e-5f);
  y_s[t] = dx * rstd * g_mlp[t] + b_mlp[t];
  __syncthreads();
  float a0 = bb1[t], a1 = bb1[64 + t];
#pragma unroll 4
  for (int i = 0; i < 64; ++i) {
    float yi = y_s[i];
    a0 = fmaf(yi, w1[i * 128 + t], a0);
    a1 = fmaf(yi, w1[i * 128 + 64 + t], a1);
  }
  a_s[t] = fmaxf(a0, 0.f);
  a_s[64 + t] = fmaxf(a1, 0.f);
  __syncthreads();
  float o = hn + bb2[t];
#pragma unroll 4
  for (int j = 0; j < 128; ++j) o = fmaf(a_s[j], w2[j * 64 + t], o);

  slots_ws[bs * 64 + t] = o;
  out_slots[bs * 64 + t] = o;  // last iteration's write is the answer
  __syncthreads();             // guard y_s reuse
  slots_ln_q(o, t, g_sl, b_sl, Wq, y_s, q_ws + bs * 64);
}

// ---------------------------------------------------------------------------
extern "C" void kernel_launch(void* const* d_in, const int* in_sizes, int n_in,
                              void* d_out, int out_size, void* d_ws, size_t ws_size,
                              hipStream_t stream) {
  const float* x      = (const float*)d_in[0];
  const float* slots  = (const float*)d_in[1];
  const float* g_in   = (const float*)d_in[2];
  const float* b_in   = (const float*)d_in[3];
  const float* g_sl   = (const float*)d_in[4];
  const float* b_sl   = (const float*)d_in[5];
  const float* g_mlp  = (const float*)d_in[6];
  const float* b_mlp  = (const float*)d_in[7];
  const float* Wq     = (const float*)d_in[8];
  const float* Wk     = (const float*)d_in[9];
  const float* Wv     = (const float*)d_in[10];
  const float* W_ih   = (const float*)d_in[11];
  const float* W_hh   = (const float*)d_in[12];
  const float* b_ih   = (const float*)d_in[13];
  const float* b_hh   = (const float*)d_in[14];
  const float* w1     = (const float*)d_in[15];
  const float* bb1    = (const float*)d_in[16];
  const float* w2     = (const float*)d_in[17];
  const float* bb2    = (const float*)d_in[18];

  float* out_slots = (float*)d_out;
  float* out_w     = (float*)d_out + (size_t)NB * NS * ND;  // 14336

  char* ws = (char*)d_ws;
  __bf16* GWt      = (__bf16*)(ws);                 // 196608 B
  float*  GWsum    = (float*)(ws + 196608);         // 512 B
  float*  BW       = (float*)(ws + 197120);         // 512 B
  float*  q_ws     = (float*)(ws + 197632);         // 57344 B
  float*  num      = (float*)(ws + 254976);         // 57344 B
  float*  den      = (float*)(ws + 312320);         // 1024 B
  float*  slots_ws = (float*)(ws + 313344);         // 57344 B
  float*  kbuf     = (float*)(ws + 370688);         // 33554432 B
  float*  vbuf     = (float*)(ws + 370688 + 33554432);  // 33554432 B
  (void)ws_size; (void)in_sizes; (void)n_in; (void)out_size;

  k_prep<<<352, 64, 0, stream>>>(Wk, Wv, g_in, b_in, slots, g_sl, b_sl, Wq,
                                 GWt, GWsum, BW, slots_ws, q_ws, num, den);
  k_gemm_kv<<<1024, 256, 0, stream>>>(x, GWt, GWsum, BW, kbuf, vbuf);
  for (int it = 0; it < 3; ++it) {  // num_iters fixed at 3 by setup_inputs
    k_attn<<<1024, 256, 0, stream>>>(kbuf, vbuf, q_ws, out_w, num, den);
    k_gru<<<224, 64, 0, stream>>>(num, den, slots_ws, W_ih, W_hh, b_ih, b_hh,
                                  w1, bb1, w2, bb2, g_mlp, b_mlp, g_sl, b_sl,
                                  Wq, q_ws, out_slots);
  }
}

// Round 2
// 699.006 us; speedup vs baseline: 1.0347x; 1.0347x over previous
//
#include <hip/hip_runtime.h>
#include <hip/hip_bf16.h>
#include <math.h>

// ---------------------------------------------------------------------------
// SlotAttention (B=32,N=4096,C=768,D=64,H=128,S=7, 3 iters)
// Stage 1: k,v = LN(x) @ [Wk|Wv]  as bf16 MFMA GEMM on RAW x:
//   xn = (x-m)*rstd*g + b  =>  k = rstd*(x @ (g*W)) - m*rstd*sum(g*W) + sum(b*W)
//   k/v stored bf16 (R2: halves kv write + attn read traffic)
// Stage 2 (x3): logits/softmax-over-S/weights + num/den atomics; GRU+MLP+next-q
// ---------------------------------------------------------------------------

typedef __bf16 bf16x8 __attribute__((ext_vector_type(8)));
typedef float  f32x4  __attribute__((ext_vector_type(4)));
typedef unsigned short u16x8 __attribute__((ext_vector_type(8)));

#define NB 32
#define NN 4096
#define NC 768
#define ND 64
#define NS 7

__device__ __forceinline__ float wave_sum64(float v) {
#pragma unroll
  for (int o = 32; o > 0; o >>= 1) v += __shfl_xor(v, o, 64);
  return v;
}

__device__ __forceinline__ float bf2f(unsigned short u) {
  union { unsigned int i; float f; } c;
  c.i = ((unsigned int)u) << 16;
  return c.f;
}

// async global->LDS, 16B per lane; lds dest = wave-uniform base + lane*16
__device__ __forceinline__ void glds16(const void* g, void* l) {
  __builtin_amdgcn_global_load_lds(
      (const __attribute__((address_space(1))) unsigned int*)(uintptr_t)g,
      (__attribute__((address_space(3))) unsigned int*)(unsigned int)(uintptr_t)l,
      16, 0, 0);
}

// LN(h; g_sl,b_sl) @ Wq for one (b,s) row; 64-thread block
__device__ __forceinline__ void slots_ln_q(float h, int t, const float* g_sl,
                                           const float* b_sl, const float* Wq,
                                           float* y_s, float* q_out) {
  float m = wave_sum64(h) * (1.0f / 64.0f);
  float dx = h - m;
  float var = wave_sum64(dx * dx) * (1.0f / 64.0f);
  float rstd = rsqrtf(var + 1e-5f);
  y_s[t] = dx * rstd * g_sl[t] + b_sl[t];
  __syncthreads();
  float q = 0.f;
#pragma unroll 8
  for (int i = 0; i < 64; ++i) q = fmaf(y_s[i], Wq[i * 64 + t], q);
  q_out[t] = q;
}

// ---------------------------------------------------------------------------
// prep: blocks 0..127  -> GWt[d][c] = bf16(g_in[c]*W[c,d]), GWsum, BW
//       blocks 128..351 -> per (b,s): slots copy, zero num/den, initial q
// ---------------------------------------------------------------------------
__global__ __launch_bounds__(64) void k_prep(
    const float* __restrict__ Wk, const float* __restrict__ Wv,
    const float* __restrict__ g_in, const float* __restrict__ b_in,
    const float* __restrict__ slots_in, const float* __restrict__ g_sl,
    const float* __restrict__ b_sl, const float* __restrict__ Wq,
    __bf16* __restrict__ GWt, float* __restrict__ GWsum, float* __restrict__ BW,
    float* __restrict__ slots_ws, float* __restrict__ q_ws,
    float* __restrict__ num, float* __restrict__ den) {
  __shared__ float y_s[64];
  int t = threadIdx.x;
  int bid = blockIdx.x;
  if (bid < 128) {
    int d = bid;
    const float* W = (d < 64) ? (Wk + d) : (Wv + (d - 64));
    float sgw = 0.f, sbw = 0.f;
    for (int j = 0; j < 12; ++j) {
      int c = t + 64 * j;
      float w = W[(size_t)c * 64];
      float gw = g_in[c] * w;
      GWt[(size_t)d * NC + c] = (__bf16)gw;
      sgw += gw;
      sbw += b_in[c] * w;
    }
    sgw = wave_sum64(sgw);
    sbw = wave_sum64(sbw);
    if (t == 0) { GWsum[d] = sgw; BW[d] = sbw; }
  } else {
    int bs = bid - 128;
    float h = slots_in[bs * 64 + t];
    slots_ws[bs * 64 + t] = h;
    num[bs * 64 + t] = 0.f;
    if (t == 0) den[bs] = 0.f;
    slots_ln_q(h, t, g_sl, b_sl, Wq, y_s, q_ws + bs * 64);
  }
}

// ---------------------------------------------------------------------------
// GEMM: (131072 x 768) @ (768 x 128) bf16 MFMA, fused LN epilogue -> bf16 k,v
// 128x128 tile, BK=64, 4 waves (2x2); B tile staged via global_load_lds DMA
// ---------------------------------------------------------------------------
#define BM 128
#define LDA 72  // A: padded (VALU-staged); B: unpadded 64 (DMA constraint)

__global__ __launch_bounds__(256) void k_gemm_kv(
    const float* __restrict__ x, const __bf16* __restrict__ GWt,
    const float* __restrict__ GWsum, const float* __restrict__ BW,
    __bf16* __restrict__ kbuf, __bf16* __restrict__ vbuf) {
  __shared__ __bf16 As[BM * LDA] __attribute__((aligned(16)));
  __shared__ __bf16 Bs[128 * 64] __attribute__((aligned(16)));
  __shared__ float mean_s[128], rstd_s[128], gws_s[128], bw_s[128];

  int t = threadIdx.x;
  int blk = blockIdx.x;
  int lane = t & 63, wave = t >> 6;
  int wr = wave >> 1, wc = wave & 1;
  int grp = lane >> 4, lr = lane & 15;
  int r = t >> 1, half = t & 1;  // A staging: row r, 32-elem half

  if (t < 128) { gws_s[t] = GWsum[t]; bw_s[t] = BW[t]; }

  f32x4 acc[4][4] = {};
  float s1 = 0.f, s2 = 0.f;

  const float* xrow = x + (size_t)(blk * BM + r) * NC + half * 32;
  // B DMA: instr j of wave w covers Bs rows [w*32+j*8, +8), 128B each
  const char* gB = (const char*)GWt + (size_t)(wave * 32 + (lane >> 3)) * (NC * 2) +
                   (lane & 7) * 16;
  char* lB = (char*)&Bs[0] + wave * 4096;  // wave-uniform

  for (int ck = 0; ck < 12; ++ck) {
    __syncthreads();
#pragma unroll
    for (int j = 0; j < 4; ++j)
      glds16(gB + ck * 128 + j * 8 * (NC * 2), lB + j * 1024);
    {  // stage A: 32 fp32 -> bf16 (+ row sum/sumsq for LN)
      const float4* p4 = (const float4*)(xrow + ck * 64);
      __bf16* dst = &As[r * LDA + half * 32];
#pragma unroll
      for (int j = 0; j < 4; ++j) {
        float4 a = p4[2 * j], b = p4[2 * j + 1];
        bf16x8 pk;
        pk[0] = (__bf16)a.x; pk[1] = (__bf16)a.y; pk[2] = (__bf16)a.z; pk[3] = (__bf16)a.w;
        pk[4] = (__bf16)b.x; pk[5] = (__bf16)b.y; pk[6] = (__bf16)b.z; pk[7] = (__bf16)b.w;
        s1 += (a.x + a.y + a.z + a.w) + (b.x + b.y + b.z + b.w);
        s2 += a.x * a.x + a.y * a.y + a.z * a.z + a.w * a.w +
              b.x * b.x + b.y * b.y + b.z * b.z + b.w * b.w;
        *(bf16x8*)(dst + j * 8) = pk;
      }
    }
    __syncthreads();
#pragma unroll
    for (int kk = 0; kk < 2; ++kk) {
      bf16x8 af[4], bfr[4];
#pragma unroll
      for (int i = 0; i < 4; ++i)
        af[i] = *(const bf16x8*)&As[(wr * 64 + i * 16 + lr) * LDA + kk * 32 + grp * 8];
#pragma unroll
      for (int i = 0; i < 4; ++i)
        bfr[i] = *(const bf16x8*)&Bs[(wc * 64 + i * 16 + lr) * 64 + kk * 32 + grp * 8];
#pragma unroll
      for (int i = 0; i < 4; ++i)
#pragma unroll
        for (int j = 0; j < 4; ++j)
          acc[i][j] = __builtin_amdgcn_mfma_f32_16x16x32_bf16(af[i], bfr[j], acc[i][j], 0, 0, 0);
    }
  }

  s1 += __shfl_xor(s1, 1, 64);
  s2 += __shfl_xor(s2, 1, 64);
  if (half == 0) {
    float m = s1 * (1.0f / 768.0f);
    float var = s2 * (1.0f / 768.0f) - m * m;
    mean_s[r] = m;
    rstd_s[r] = rsqrtf(var + 1e-5f);
  }
  __syncthreads();

  // epilogue: C/D layout col=lane&15, row=(lane>>4)*4+e  [m89/m91 verified]
#pragma unroll
  for (int i = 0; i < 4; ++i) {
#pragma unroll
    for (int j = 0; j < 4; ++j) {
      int colb = wc * 64 + j * 16 + lr;
      float gw = gws_s[colb], bw = bw_s[colb];
      __bf16* obuf = (colb < 64) ? kbuf : vbuf;
      int ocol = colb & 63;
#pragma unroll
      for (int e = 0; e < 4; ++e) {
        int row = wr * 64 + i * 16 + grp * 4 + e;
        float rs = rstd_s[row], m = mean_s[row];
        float val = rs * acc[i][j][e] - m * rs * gw + bw;
        obuf[(size_t)(blk * BM + row) * 64 + ocol] = (__bf16)val;
      }
    }
  }
}

// ---------------------------------------------------------------------------
// attention: per (b, 128-n chunk): logits (q.k), softmax over S=7,
// weights (last iter only), den partials, num partials (w @ v) -> atomics
// ---------------------------------------------------------------------------
__global__ __launch_bounds__(256) void k_attn(
    const __bf16* __restrict__ kbuf, const __bf16* __restrict__ vbuf,
    const float* __restrict__ q_ws, float* __restrict__ out_w,
    float* __restrict__ num, float* __restrict__ den, int write_w) {
  __shared__ float q_s[7 * 64];
  __shared__ float w_s[7 * 130];
  __shared__ float v_s[128 * 68] __attribute__((aligned(16)));
  __shared__ float den_p[28];
  __shared__ float red[7 * 4 * 64];

  int t = threadIdx.x;
  int b = blockIdx.x >> 5;
  int n0 = (blockIdx.x & 31) * 128;

  for (int idx = t; idx < 448; idx += 256) q_s[idx] = q_ws[b * 448 + idx];
  __syncthreads();

  int nl = t >> 1, dh = t & 1;  // lane pair splits the 64-d dot
  float kf[32];
  {
    const u16x8* kp = (const u16x8*)(kbuf + ((size_t)b * NN + n0 + nl) * 64 + dh * 32);
#pragma unroll
    for (int j = 0; j < 4; ++j) {
      u16x8 a = kp[j];
#pragma unroll
      for (int m = 0; m < 8; ++m) kf[j * 8 + m] = bf2f(a[m]);
    }
  }

  float lg[7];
#pragma unroll
  for (int s = 0; s < 7; ++s) {
    const float* qv = &q_s[s * 64 + dh * 32];
    float d0 = 0.f;
#pragma unroll
    for (int j = 0; j < 32; ++j) d0 = fmaf(kf[j], qv[j], d0);
    d0 += __shfl_xor(d0, 1, 64);
    lg[s] = d0 * 0.125f;  // D^-0.5
  }
  float mx = lg[0];
#pragma unroll
  for (int s = 1; s < 7; ++s) mx = fmaxf(mx, lg[s]);
  float sum = 0.f;
#pragma unroll
  for (int s = 0; s < 7; ++s) { lg[s] = __expf(lg[s] - mx); sum += lg[s]; }
  float inv = 1.0f / sum;
  if (dh == 0) {
#pragma unroll
    for (int s = 0; s < 7; ++s) w_s[s * 130 + nl] = lg[s] * inv;
  }
  __syncthreads();

  if (write_w) {  // only the last iteration's weights are the output
    for (int idx = t; idx < 896; idx += 256) {
      int s = idx >> 7, n = idx & 127;
      out_w[(size_t)b * 7 * NN + (size_t)s * NN + n0 + n] = w_s[s * 130 + n];
    }
  }
  if (t < 28) {
    int s = t >> 2, qq = t & 3;
    float ds = 0.f;
    for (int j = 0; j < 32; ++j) ds += w_s[s * 130 + qq * 32 + j];
    den_p[t] = ds;
  }
  {  // stage v tile (bf16 -> f32 LDS)
    const u16x8* vp = (const u16x8*)(vbuf + ((size_t)b * NN + n0 + nl) * 64 + dh * 32);
    float4* dst = (float4*)&v_s[nl * 68 + dh * 32];
#pragma unroll
    for (int j = 0; j < 4; ++j) {
      u16x8 a = vp[j];
      float4 lo = {bf2f(a[0]), bf2f(a[1]), bf2f(a[2]), bf2f(a[3])};
      float4 hi = {bf2f(a[4]), bf2f(a[5]), bf2f(a[6]), bf2f(a[7])};
      dst[2 * j] = lo;
      dst[2 * j + 1] = hi;
    }
  }
  __syncthreads();
  if (t < 7)
    atomicAdd(&den[b * 7 + t],
              den_p[4 * t] + den_p[4 * t + 1] + den_p[4 * t + 2] + den_p[4 * t + 3]);

  // num[s][d] partials: wave qtr handles 32 n's; w_s read is wave-uniform
  int d = t & 63, qtr = t >> 6;
  float np_[7] = {0, 0, 0, 0, 0, 0, 0};
  for (int j = 0; j < 32; ++j) {
    int n = qtr * 32 + j;
    float vv = v_s[n * 68 + d];
#pragma unroll
    for (int s = 0; s < 7; ++s) np_[s] = fmaf(w_s[s * 130 + n], vv, np_[s]);
  }
#pragma unroll
  for (int s = 0; s < 7; ++s) red[(s * 4 + qtr) * 64 + d] = np_[s];
  __syncthreads();
  for (int idx = t; idx < 448; idx += 256) {
    int s = idx >> 6, dd = idx & 63;
    float sm = red[(s * 4 + 0) * 64 + dd] + red[(s * 4 + 1) * 64 + dd] +
               red[(s * 4 + 2) * 64 + dd] + red[(s * 4 + 3) * 64 + dd];
    atomicAdd(&num[(b * 7 + s) * 64 + dd], sm);
  }
}

// ---------------------------------------------------------------------------
// GRU + residual MLP + next-iteration q; zeroes num/den for next iter.
// ---------------------------------------------------------------------------
__global__ __launch_bounds__(64) void k_gru(
    float* __restrict__ num, float* __restrict__ den,
    float* __restrict__ slots_ws, const float* __restrict__ W_ih,
    const float* __restrict__ W_hh, const float* __restrict__ b_ih,
    const float* __restrict__ b_hh, const float* __restrict__ w1,
    const float* __restrict__ bb1, const float* __restrict__ w2,
    const float* __restrict__ bb2, const float* __restrict__ g_mlp,
    const float* __restrict__ b_mlp, const float* __restrict__ g_sl,
    const float* __restrict__ b_sl, const float* __restrict__ Wq,
    float* __restrict__ q_ws, float* __restrict__ out_slots) {
  __shared__ float att_s[64], h_s[64], y_s[64], a_s[128];
  int t = threadIdx.x;
  int bs = blockIdx.x;

  float h = slots_ws[bs * 64 + t];
  float dn = den[bs];
  float at = num[bs * 64 + t] / (dn + 1e-8f);
  att_s[t] = at;
  h_s[t] = h;
  __syncthreads();
  num[bs * 64 + t] = 0.f;  // zero for next iteration
  if (t == 0) den[bs] = 0.f;

  float gi0 = b_ih[t], gi1 = b_ih[64 + t], gi2 = b_ih[128 + t];
  float gh0 = b_hh[t], gh1 = b_hh[64 + t], gh2 = b_hh[128 + t];
#pragma unroll 4
  for (int i = 0; i < 64; ++i) {
    float ai = att_s[i], hi = h_s[i];
    const float* wi = W_ih + i * 192 + t;
    const float* wh = W_hh + i * 192 + t;
    gi0 = fmaf(ai, wi[0], gi0);
    gi1 = fmaf(ai, wi[64], gi1);
    gi2 = fmaf(ai, wi[128], gi2);
    gh0 = fmaf(hi, wh[0], gh0);
    gh1 = fmaf(hi, wh[64], gh1);
    gh2 = fmaf(hi, wh[128], gh2);
  }
  float rr = 1.f / (1.f + __expf(-(gi0 + gh0)));
  float zz = 1.f / (1.f + __expf(-(gi1 + gh1)));
  float nn = tanhf(gi2 + rr * gh2);
  float hn = (1.f - zz) * nn + zz * h;

  // residual MLP with LN
  float m = wave_sum64(hn) * (1.f / 64.f);
  float dx = hn - m;
  float var = wave_sum64(dx * dx) * (1.f / 64.f);
  float rstd = rsqrtf(var + 1e-5f);
  y_s[t] = dx * rstd * g_mlp[t] + b_mlp[t];
  __syncthreads();
  float a0 = bb1[t], a1 = bb1[64 + t];
#pragma unroll 4
  for (int i = 0; i < 64; ++i) {
    float yi = y_s[i];
    a0 = fmaf(yi, w1[i * 128 + t], a0);
    a1 = fmaf(yi, w1[i * 128 + 64 + t], a1);
  }
  a_s[t] = fmaxf(a0, 0.f);
  a_s[64 + t] = fmaxf(a1, 0.f);
  __syncthreads();
  float o = hn + bb2[t];
#pragma unroll 4
  for (int j = 0; j < 128; ++j) o = fmaf(a_s[j], w2[j * 64 + t], o);

  slots_ws[bs * 64 + t] = o;
  out_slots[bs * 64 + t] = o;
  __syncthreads();  // guard y_s reuse
  slots_ln_q(o, t, g_sl, b_sl, Wq, y_s, q_ws + bs * 64);
}

// ---------------------------------------------------------------------------
extern "C" void kernel_launch(void* const* d_in, const int* in_sizes, int n_in,
                              void* d_out, int out_size, void* d_ws, size_t ws_size,
                              hipStream_t stream) {
  const float* x      = (const float*)d_in[0];
  const float* slots  = (const float*)d_in[1];
  const float* g_in   = (const float*)d_in[2];
  const float* b_in   = (const float*)d_in[3];
  const float* g_sl   = (const float*)d_in[4];
  const float* b_sl   = (const float*)d_in[5];
  const float* g_mlp  = (const float*)d_in[6];
  const float* b_mlp  = (const float*)d_in[7];
  const float* Wq     = (const float*)d_in[8];
  const float* Wk     = (const float*)d_in[9];
  const float* Wv     = (const float*)d_in[10];
  const float* W_ih   = (const float*)d_in[11];
  const float* W_hh   = (const float*)d_in[12];
  const float* b_ih   = (const float*)d_in[13];
  const float* b_hh   = (const float*)d_in[14];
  const float* w1     = (const float*)d_in[15];
  const float* bb1    = (const float*)d_in[16];
  const float* w2     = (const float*)d_in[17];
  const float* bb2    = (const float*)d_in[18];

  float* out_slots = (float*)d_out;
  float* out_w     = (float*)d_out + (size_t)NB * NS * ND;  // 14336

  char* ws = (char*)d_ws;
  __bf16* GWt      = (__bf16*)(ws);                 // 196608 B
  float*  GWsum    = (float*)(ws + 196608);         // 512 B
  float*  BW       = (float*)(ws + 197120);         // 512 B
  float*  q_ws     = (float*)(ws + 197632);         // 57344 B
  float*  num      = (float*)(ws + 254976);         // 57344 B
  float*  den      = (float*)(ws + 312320);         // 1024 B
  float*  slots_ws = (float*)(ws + 313344);         // 57344 B
  __bf16* kbuf     = (__bf16*)(ws + 370688);        // 16777216 B
  __bf16* vbuf     = (__bf16*)(ws + 370688 + 16777216);  // 16777216 B
  (void)ws_size; (void)in_sizes; (void)n_in; (void)out_size;

  k_prep<<<352, 64, 0, stream>>>(Wk, Wv, g_in, b_in, slots, g_sl, b_sl, Wq,
                                 GWt, GWsum, BW, slots_ws, q_ws, num, den);
  k_gemm_kv<<<1024, 256, 0, stream>>>(x, GWt, GWsum, BW, kbuf, vbuf);
  for (int it = 0; it < 3; ++it) {  // num_iters fixed at 3 by setup_inputs
    k_attn<<<1024, 256, 0, stream>>>(kbuf, vbuf, q_ws, out_w, num, den,
                                     it == 2 ? 1 : 0);
    k_gru<<<224, 64, 0, stream>>>(num, den, slots_ws, W_ih, W_hh, b_ih, b_hh,
                                  w1, bb1, w2, bb2, g_mlp, b_mlp, g_sl, b_sl,
                                  Wq, q_ws, out_slots);
  }
}

// Round 3
// 698.897 us; speedup vs baseline: 1.0348x; 1.0002x over previous
//
#include <hip/hip_runtime.h>
#include <hip/hip_bf16.h>
#include <math.h>

// ---------------------------------------------------------------------------
// SlotAttention (B=32,N=4096,C=768,D=64,H=128,S=7, 3 iters)
// Stage 1: k,v = LN(x) @ [Wk|Wv]  as bf16 MFMA GEMM on RAW x, with the
//   LN folded into a rank-1 epilogue, AND iteration-1 attention fused into
//   the epilogue (softmax over S=7 is per-n => tile-local).
// Stage 2 (x2): attn kernel (iters 2,3) + GRU/MLP/next-q kernel (x3)
// ---------------------------------------------------------------------------

typedef __bf16 bf16x8 __attribute__((ext_vector_type(8)));
typedef float  f32x4  __attribute__((ext_vector_type(4)));
typedef unsigned short u16x8 __attribute__((ext_vector_type(8)));

#define NB 32
#define NN 4096
#define NC 768
#define ND 64
#define NS 7

__device__ __forceinline__ float wave_sum64(float v) {
#pragma unroll
  for (int o = 32; o > 0; o >>= 1) v += __shfl_xor(v, o, 64);
  return v;
}

__device__ __forceinline__ float bf2f(unsigned short u) {
  union { unsigned int i; float f; } c;
  c.i = ((unsigned int)u) << 16;
  return c.f;
}

// async global->LDS, 16B per lane; lds dest = wave-uniform base + lane*16
__device__ __forceinline__ void glds16(const void* g, void* l) {
  __builtin_amdgcn_global_load_lds(
      (const __attribute__((address_space(1))) unsigned int*)(uintptr_t)g,
      (__attribute__((address_space(3))) unsigned int*)(unsigned int)(uintptr_t)l,
      16, 0, 0);
}

// LN(h; g_sl,b_sl) @ Wq for one (b,s) row; 64-thread block
__device__ __forceinline__ void slots_ln_q(float h, int t, const float* g_sl,
                                           const float* b_sl, const float* Wq,
                                           float* y_s, float* q_out) {
  float m = wave_sum64(h) * (1.0f / 64.0f);
  float dx = h - m;
  float var = wave_sum64(dx * dx) * (1.0f / 64.0f);
  float rstd = rsqrtf(var + 1e-5f);
  y_s[t] = dx * rstd * g_sl[t] + b_sl[t];
  __syncthreads();
  float q = 0.f;
#pragma unroll 8
  for (int i = 0; i < 64; ++i) q = fmaf(y_s[i], Wq[i * 64 + t], q);
  q_out[t] = q;
}

// ---------------------------------------------------------------------------
// prep: blocks 0..127  -> GWt[d][c] = bf16(g_in[c]*W[c,d]), GWsum, BW
//       blocks 128..351 -> per (b,s): slots copy, zero num/den, initial q
// ---------------------------------------------------------------------------
__global__ __launch_bounds__(64) void k_prep(
    const float* __restrict__ Wk, const float* __restrict__ Wv,
    const float* __restrict__ g_in, const float* __restrict__ b_in,
    const float* __restrict__ slots_in, const float* __restrict__ g_sl,
    const float* __restrict__ b_sl, const float* __restrict__ Wq,
    __bf16* __restrict__ GWt, float* __restrict__ GWsum, float* __restrict__ BW,
    float* __restrict__ slots_ws, float* __restrict__ q_ws,
    float* __restrict__ num, float* __restrict__ den) {
  __shared__ float y_s[64];
  int t = threadIdx.x;
  int bid = blockIdx.x;
  if (bid < 128) {
    int d = bid;
    const float* W = (d < 64) ? (Wk + d) : (Wv + (d - 64));
    float sgw = 0.f, sbw = 0.f;
    for (int j = 0; j < 12; ++j) {
      int c = t + 64 * j;
      float w = W[(size_t)c * 64];
      float gw = g_in[c] * w;
      GWt[(size_t)d * NC + c] = (__bf16)gw;
      sgw += gw;
      sbw += b_in[c] * w;
    }
    sgw = wave_sum64(sgw);
    sbw = wave_sum64(sbw);
    if (t == 0) { GWsum[d] = sgw; BW[d] = sbw; }
  } else {
    int bs = bid - 128;
    float h = slots_in[bs * 64 + t];
    slots_ws[bs * 64 + t] = h;
    num[bs * 64 + t] = 0.f;
    if (t == 0) den[bs] = 0.f;
    slots_ln_q(h, t, g_sl, b_sl, Wq, y_s, q_ws + bs * 64);
  }
}

// ---------------------------------------------------------------------------
// GEMM: (131072 x 768) @ (768 x 128) bf16 MFMA, LN epilogue -> bf16 k,v,
// then iter-1 attention fused (tile-local softmax over S, num/den atomics).
// 128x128 tile, BK=64, 4 waves (2x2); B tile staged via global_load_lds DMA.
// ---------------------------------------------------------------------------
#define BM 128
#define LDA 72   // A LDS leading dim (bf16)
#define LDKV 136 // fused kv tile leading dim (bf16)

__global__ __launch_bounds__(256) void k_gemm_kv(
    const float* __restrict__ x, const __bf16* __restrict__ GWt,
    const float* __restrict__ GWsum, const float* __restrict__ BW,
    const float* __restrict__ q_ws, __bf16* __restrict__ kbuf,
    __bf16* __restrict__ vbuf, float* __restrict__ num,
    float* __restrict__ den) {
  // LDS: stats | union{ As+Bs (gemm) , kv tile (attn) } | w_s den_p red q_s
  __shared__ char smem[2048 + 34816 + 3640 + 112 + 7168 + 1792]
      __attribute__((aligned(16)));
  float* mean_s = (float*)smem;
  float* rstd_s = (float*)(smem + 512);
  float* gws_s  = (float*)(smem + 1024);
  float* bw_s   = (float*)(smem + 1536);
  __bf16* As    = (__bf16*)(smem + 2048);          // 128*72*2  = 18432
  __bf16* Bs    = (__bf16*)(smem + 2048 + 18432);  // 128*64*2  = 16384
  __bf16* kv_s  = (__bf16*)(smem + 2048);          // 128*136*2 = 34816 (overlay)
  float* w_s    = (float*)(smem + 2048 + 34816);             // 7*130
  float* den_p  = (float*)(smem + 2048 + 34816 + 3640);      // 28
  float* red_s  = (float*)(smem + 2048 + 34816 + 3640 + 112);    // 7*4*64
  float* q_s    = (float*)(smem + 2048 + 34816 + 3640 + 112 + 7168);  // 448

  int t = threadIdx.x;
  int blk = blockIdx.x;
  int b = blk >> 5;
  int n0 = (blk & 31) * 128;
  int lane = t & 63, wave = t >> 6;
  int wr = wave >> 1, wc = wave & 1;
  int grp = lane >> 4, lr = lane & 15;
  int r = t >> 1, half = t & 1;  // A staging: row r, 32-elem half

  if (t < 128) { gws_s[t] = GWsum[t]; bw_s[t] = BW[t]; }
  for (int idx = t; idx < 448; idx += 256) q_s[idx] = q_ws[b * 448 + idx];

  f32x4 acc[4][4] = {};
  float s1 = 0.f, s2 = 0.f;

  const float* xrow = x + (size_t)(blk * BM + r) * NC + half * 32;
  const char* gB = (const char*)GWt + (size_t)(wave * 32 + (lane >> 3)) * (NC * 2) +
                   (lane & 7) * 16;
  char* lB = (char*)&Bs[0] + wave * 4096;  // wave-uniform

  for (int ck = 0; ck < 12; ++ck) {
    __syncthreads();
#pragma unroll
    for (int j = 0; j < 4; ++j)
      glds16(gB + ck * 128 + j * 8 * (NC * 2), lB + j * 1024);
    {  // stage A: 32 fp32 -> bf16 (+ row sum/sumsq for LN)
      const float4* p4 = (const float4*)(xrow + ck * 64);
      __bf16* dst = &As[r * LDA + half * 32];
#pragma unroll
      for (int j = 0; j < 4; ++j) {
        float4 a = p4[2 * j], bb = p4[2 * j + 1];
        bf16x8 pk;
        pk[0] = (__bf16)a.x; pk[1] = (__bf16)a.y; pk[2] = (__bf16)a.z; pk[3] = (__bf16)a.w;
        pk[4] = (__bf16)bb.x; pk[5] = (__bf16)bb.y; pk[6] = (__bf16)bb.z; pk[7] = (__bf16)bb.w;
        s1 += (a.x + a.y + a.z + a.w) + (bb.x + bb.y + bb.z + bb.w);
        s2 += a.x * a.x + a.y * a.y + a.z * a.z + a.w * a.w +
              bb.x * bb.x + bb.y * bb.y + bb.z * bb.z + bb.w * bb.w;
        *(bf16x8*)(dst + j * 8) = pk;
      }
    }
    __syncthreads();
#pragma unroll
    for (int kk = 0; kk < 2; ++kk) {
      bf16x8 af[4], bfr[4];
#pragma unroll
      for (int i = 0; i < 4; ++i)
        af[i] = *(const bf16x8*)&As[(wr * 64 + i * 16 + lr) * LDA + kk * 32 + grp * 8];
#pragma unroll
      for (int i = 0; i < 4; ++i)
        bfr[i] = *(const bf16x8*)&Bs[(wc * 64 + i * 16 + lr) * 64 + kk * 32 + grp * 8];
#pragma unroll
      for (int i = 0; i < 4; ++i)
#pragma unroll
        for (int j = 0; j < 4; ++j)
          acc[i][j] = __builtin_amdgcn_mfma_f32_16x16x32_bf16(af[i], bfr[j], acc[i][j], 0, 0, 0);
    }
  }

  s1 += __shfl_xor(s1, 1, 64);
  s2 += __shfl_xor(s2, 1, 64);
  if (half == 0) {
    float m = s1 * (1.0f / 768.0f);
    float var = s2 * (1.0f / 768.0f) - m * m;
    mean_s[r] = m;
    rstd_s[r] = rsqrtf(var + 1e-5f);
  }
  __syncthreads();  // also: last MFMA reads of As/Bs done -> kv_s overlay safe

  // epilogue: C/D layout col=lane&15, row=(lane>>4)*4+e  [m89/m91 verified]
#pragma unroll
  for (int i = 0; i < 4; ++i) {
#pragma unroll
    for (int j = 0; j < 4; ++j) {
      int colb = wc * 64 + j * 16 + lr;
      float gw = gws_s[colb], bw = bw_s[colb];
      __bf16* obuf = (colb < 64) ? kbuf : vbuf;
      int ocol = colb & 63;
#pragma unroll
      for (int e = 0; e < 4; ++e) {
        int row = wr * 64 + i * 16 + grp * 4 + e;
        float rs = rstd_s[row], m = mean_s[row];
        __bf16 val = (__bf16)(rs * acc[i][j][e] - m * rs * gw + bw);
        obuf[(size_t)(blk * BM + row) * 64 + ocol] = val;
        kv_s[row * LDKV + colb] = val;  // fused iter-1 attention input
      }
    }
  }
  __syncthreads();

  // ---- fused iteration-1 attention on the local tile ----
  int nl = t >> 1, dh = t & 1;  // lane pair splits the 64-d dot
  float kf[32];
  {
    const u16x8* kp = (const u16x8*)&kv_s[nl * LDKV + dh * 32];
#pragma unroll
    for (int j = 0; j < 4; ++j) {
      u16x8 a = kp[j];
#pragma unroll
      for (int m = 0; m < 8; ++m) kf[j * 8 + m] = bf2f(a[m]);
    }
  }
  float lg[7];
#pragma unroll
  for (int s = 0; s < 7; ++s) {
    const float* qv = &q_s[s * 64 + dh * 32];
    float d0 = 0.f;
#pragma unroll
    for (int j = 0; j < 32; ++j) d0 = fmaf(kf[j], qv[j], d0);
    d0 += __shfl_xor(d0, 1, 64);
    lg[s] = d0 * 0.125f;  // D^-0.5
  }
  float mx = lg[0];
#pragma unroll
  for (int s = 1; s < 7; ++s) mx = fmaxf(mx, lg[s]);
  float sum = 0.f;
#pragma unroll
  for (int s = 0; s < 7; ++s) { lg[s] = __expf(lg[s] - mx); sum += lg[s]; }
  float inv = 1.0f / sum;
  if (dh == 0) {
#pragma unroll
    for (int s = 0; s < 7; ++s) w_s[s * 130 + nl] = lg[s] * inv;
  }
  __syncthreads();

  if (t < 28) {
    int s = t >> 2, qq = t & 3;
    float ds = 0.f;
    for (int j = 0; j < 32; ++j) ds += w_s[s * 130 + qq * 32 + j];
    den_p[t] = ds;
  }
  __syncthreads();
  if (t < 7)
    atomicAdd(&den[b * 7 + t],
              den_p[4 * t] + den_p[4 * t + 1] + den_p[4 * t + 2] + den_p[4 * t + 3]);

  int d = t & 63, qtr = t >> 6;
  float np_[7] = {0, 0, 0, 0, 0, 0, 0};
  for (int j = 0; j < 32; ++j) {
    int n = qtr * 32 + j;
    float vv = bf2f(*(const unsigned short*)&kv_s[n * LDKV + 64 + d]);
#pragma unroll
    for (int s = 0; s < 7; ++s) np_[s] = fmaf(w_s[s * 130 + n], vv, np_[s]);
  }
#pragma unroll
  for (int s = 0; s < 7; ++s) red_s[(s * 4 + qtr) * 64 + d] = np_[s];
  __syncthreads();
  for (int idx = t; idx < 448; idx += 256) {
    int s = idx >> 6, dd = idx & 63;
    float sm = red_s[(s * 4 + 0) * 64 + dd] + red_s[(s * 4 + 1) * 64 + dd] +
               red_s[(s * 4 + 2) * 64 + dd] + red_s[(s * 4 + 3) * 64 + dd];
    atomicAdd(&num[(b * 7 + s) * 64 + dd], sm);
  }
}

// ---------------------------------------------------------------------------
// attention (iters 2,3): per (b, 128-n chunk): logits, softmax over S=7,
// weights (last iter only), den partials, num partials (w @ v) -> atomics
// ---------------------------------------------------------------------------
__global__ __launch_bounds__(256) void k_attn(
    const __bf16* __restrict__ kbuf, const __bf16* __restrict__ vbuf,
    const float* __restrict__ q_ws, float* __restrict__ out_w,
    float* __restrict__ num, float* __restrict__ den, int write_w) {
  __shared__ float q_s[7 * 64];
  __shared__ float w_s[7 * 130];
  __shared__ float v_s[128 * 68] __attribute__((aligned(16)));
  __shared__ float den_p[28];
  __shared__ float red[7 * 4 * 64];

  int t = threadIdx.x;
  int b = blockIdx.x >> 5;
  int n0 = (blockIdx.x & 31) * 128;

  for (int idx = t; idx < 448; idx += 256) q_s[idx] = q_ws[b * 448 + idx];
  __syncthreads();

  int nl = t >> 1, dh = t & 1;
  float kf[32];
  {
    const u16x8* kp = (const u16x8*)(kbuf + ((size_t)b * NN + n0 + nl) * 64 + dh * 32);
#pragma unroll
    for (int j = 0; j < 4; ++j) {
      u16x8 a = kp[j];
#pragma unroll
      for (int m = 0; m < 8; ++m) kf[j * 8 + m] = bf2f(a[m]);
    }
  }

  float lg[7];
#pragma unroll
  for (int s = 0; s < 7; ++s) {
    const float* qv = &q_s[s * 64 + dh * 32];
    float d0 = 0.f;
#pragma unroll
    for (int j = 0; j < 32; ++j) d0 = fmaf(kf[j], qv[j], d0);
    d0 += __shfl_xor(d0, 1, 64);
    lg[s] = d0 * 0.125f;
  }
  float mx = lg[0];
#pragma unroll
  for (int s = 1; s < 7; ++s) mx = fmaxf(mx, lg[s]);
  float sum = 0.f;
#pragma unroll
  for (int s = 0; s < 7; ++s) { lg[s] = __expf(lg[s] - mx); sum += lg[s]; }
  float inv = 1.0f / sum;
  if (dh == 0) {
#pragma unroll
    for (int s = 0; s < 7; ++s) w_s[s * 130 + nl] = lg[s] * inv;
  }
  __syncthreads();

  if (write_w) {
    for (int idx = t; idx < 896; idx += 256) {
      int s = idx >> 7, n = idx & 127;
      out_w[(size_t)b * 7 * NN + (size_t)s * NN + n0 + n] = w_s[s * 130 + n];
    }
  }
  if (t < 28) {
    int s = t >> 2, qq = t & 3;
    float ds = 0.f;
    for (int j = 0; j < 32; ++j) ds += w_s[s * 130 + qq * 32 + j];
    den_p[t] = ds;
  }
  {  // stage v tile (bf16 -> f32 LDS)
    const u16x8* vp = (const u16x8*)(vbuf + ((size_t)b * NN + n0 + nl) * 64 + dh * 32);
    float4* dst = (float4*)&v_s[nl * 68 + dh * 32];
#pragma unroll
    for (int j = 0; j < 4; ++j) {
      u16x8 a = vp[j];
      float4 lo = {bf2f(a[0]), bf2f(a[1]), bf2f(a[2]), bf2f(a[3])};
      float4 hi = {bf2f(a[4]), bf2f(a[5]), bf2f(a[6]), bf2f(a[7])};
      dst[2 * j] = lo;
      dst[2 * j + 1] = hi;
    }
  }
  __syncthreads();
  if (t < 7)
    atomicAdd(&den[b * 7 + t],
              den_p[4 * t] + den_p[4 * t + 1] + den_p[4 * t + 2] + den_p[4 * t + 3]);

  int d = t & 63, qtr = t >> 6;
  float np_[7] = {0, 0, 0, 0, 0, 0, 0};
  for (int j = 0; j < 32; ++j) {
    int n = qtr * 32 + j;
    float vv = v_s[n * 68 + d];
#pragma unroll
    for (int s = 0; s < 7; ++s) np_[s] = fmaf(w_s[s * 130 + n], vv, np_[s]);
  }
#pragma unroll
  for (int s = 0; s < 7; ++s) red[(s * 4 + qtr) * 64 + d] = np_[s];
  __syncthreads();
  for (int idx = t; idx < 448; idx += 256) {
    int s = idx >> 6, dd = idx & 63;
    float sm = red[(s * 4 + 0) * 64 + dd] + red[(s * 4 + 1) * 64 + dd] +
               red[(s * 4 + 2) * 64 + dd] + red[(s * 4 + 3) * 64 + dd];
    atomicAdd(&num[(b * 7 + s) * 64 + dd], sm);
  }
}

// ---------------------------------------------------------------------------
// GRU + residual MLP + next-iteration q; zeroes num/den for next iter.
// ---------------------------------------------------------------------------
__global__ __launch_bounds__(64) void k_gru(
    float* __restrict__ num, float* __restrict__ den,
    float* __restrict__ slots_ws, const float* __restrict__ W_ih,
    const float* __restrict__ W_hh, const float* __restrict__ b_ih,
    const float* __restrict__ b_hh, const float* __restrict__ w1,
    const float* __restrict__ bb1, const float* __restrict__ w2,
    const float* __restrict__ bb2, const float* __restrict__ g_mlp,
    const float* __restrict__ b_mlp, const float* __restrict__ g_sl,
    const float* __restrict__ b_sl, const float* __restrict__ Wq,
    float* __restrict__ q_ws, float* __restrict__ out_slots) {
  __shared__ float att_s[64], h_s[64], y_s[64], a_s[128];
  int t = threadIdx.x;
  int bs = blockIdx.x;

  float h = slots_ws[bs * 64 + t];
  float dn = den[bs];
  float at = num[bs * 64 + t] / (dn + 1e-8f);
  att_s[t] = at;
  h_s[t] = h;
  __syncthreads();
  num[bs * 64 + t] = 0.f;  // zero for next iteration
  if (t == 0) den[bs] = 0.f;

  float gi0 = b_ih[t], gi1 = b_ih[64 + t], gi2 = b_ih[128 + t];
  float gh0 = b_hh[t], gh1 = b_hh[64 + t], gh2 = b_hh[128 + t];
#pragma unroll 4
  for (int i = 0; i < 64; ++i) {
    float ai = att_s[i], hi = h_s[i];
    const float* wi = W_ih + i * 192 + t;
    const float* wh = W_hh + i * 192 + t;
    gi0 = fmaf(ai, wi[0], gi0);
    gi1 = fmaf(ai, wi[64], gi1);
    gi2 = fmaf(ai, wi[128], gi2);
    gh0 = fmaf(hi, wh[0], gh0);
    gh1 = fmaf(hi, wh[64], gh1);
    gh2 = fmaf(hi, wh[128], gh2);
  }
  float rr = 1.f / (1.f + __expf(-(gi0 + gh0)));
  float zz = 1.f / (1.f + __expf(-(gi1 + gh1)));
  float nn = tanhf(gi2 + rr * gh2);
  float hn = (1.f - zz) * nn + zz * h;

  // residual MLP with LN
  float m = wave_sum64(hn) * (1.f / 64.f);
  float dx = hn - m;
  float var = wave_sum64(dx * dx) * (1.f / 64.f);
  float rstd = rsqrtf(var + 1e-5f);
  y_s[t] = dx * rstd * g_mlp[t] + b_mlp[t];
  __syncthreads();
  float a0 = bb1[t], a1 = bb1[64 + t];
#pragma unroll 4
  for (int i = 0; i < 64; ++i) {
    float yi = y_s[i];
    a0 = fmaf(yi, w1[i * 128 + t], a0);
    a1 = fmaf(yi, w1[i * 128 + 64 + t], a1);
  }
  a_s[t] = fmaxf(a0, 0.f);
  a_s[64 + t] = fmaxf(a1, 0.f);
  __syncthreads();
  float o = hn + bb2[t];
#pragma unroll 4
  for (int j = 0; j < 128; ++j) o = fmaf(a_s[j], w2[j * 64 + t], o);

  slots_ws[bs * 64 + t] = o;
  out_slots[bs * 64 + t] = o;
  __syncthreads();  // guard y_s reuse
  slots_ln_q(o, t, g_sl, b_sl, Wq, y_s, q_ws + bs * 64);
}

// ---------------------------------------------------------------------------
extern "C" void kernel_launch(void* const* d_in, const int* in_sizes, int n_in,
                              void* d_out, int out_size, void* d_ws, size_t ws_size,
                              hipStream_t stream) {
  const float* x      = (const float*)d_in[0];
  const float* slots  = (const float*)d_in[1];
  const float* g_in   = (const float*)d_in[2];
  const float* b_in   = (const float*)d_in[3];
  const float* g_sl   = (const float*)d_in[4];
  const float* b_sl   = (const float*)d_in[5];
  const float* g_mlp  = (const float*)d_in[6];
  const float* b_mlp  = (const float*)d_in[7];
  const float* Wq     = (const float*)d_in[8];
  const float* Wk     = (const float*)d_in[9];
  const float* Wv     = (const float*)d_in[10];
  const float* W_ih   = (const float*)d_in[11];
  const float* W_hh   = (const float*)d_in[12];
  const float* b_ih   = (const float*)d_in[13];
  const float* b_hh   = (const float*)d_in[14];
  const float* w1     = (const float*)d_in[15];
  const float* bb1    = (const float*)d_in[16];
  const float* w2     = (const float*)d_in[17];
  const float* bb2    = (const float*)d_in[18];

  float* out_slots = (float*)d_out;
  float* out_w     = (float*)d_out + (size_t)NB * NS * ND;  // 14336

  char* ws = (char*)d_ws;
  __bf16* GWt      = (__bf16*)(ws);                 // 196608 B
  float*  GWsum    = (float*)(ws + 196608);         // 512 B
  float*  BW       = (float*)(ws + 197120);         // 512 B
  float*  q_ws     = (float*)(ws + 197632);         // 57344 B
  float*  num      = (float*)(ws + 254976);         // 57344 B
  float*  den      = (float*)(ws + 312320);         // 1024 B
  float*  slots_ws = (float*)(ws + 313344);         // 57344 B
  __bf16* kbuf     = (__bf16*)(ws + 370688);        // 16777216 B
  __bf16* vbuf     = (__bf16*)(ws + 370688 + 16777216);  // 16777216 B
  (void)ws_size; (void)in_sizes; (void)n_in; (void)out_size;

  k_prep<<<352, 64, 0, stream>>>(Wk, Wv, g_in, b_in, slots, g_sl, b_sl, Wq,
                                 GWt, GWsum, BW, slots_ws, q_ws, num, den);
  // GEMM with fused iteration-1 attention
  k_gemm_kv<<<1024, 256, 0, stream>>>(x, GWt, GWsum, BW, q_ws, kbuf, vbuf,
                                      num, den);
  k_gru<<<224, 64, 0, stream>>>(num, den, slots_ws, W_ih, W_hh, b_ih, b_hh,
                                w1, bb1, w2, bb2, g_mlp, b_mlp, g_sl, b_sl,
                                Wq, q_ws, out_slots);
  for (int it = 1; it < 3; ++it) {
    k_attn<<<1024, 256, 0, stream>>>(kbuf, vbuf, q_ws, out_w, num, den,
                                     it == 2 ? 1 : 0);
    k_gru<<<224, 64, 0, stream>>>(num, den, slots_ws, W_ih, W_hh, b_ih, b_hh,
                                  w1, bb1, w2, bb2, g_mlp, b_mlp, g_sl, b_sl,
                                  Wq, q_ws, out_slots);
  }
}